// Round 10
// baseline (147.162 us; speedup 1.0000x reference)
//
#include <hip/hip_runtime.h>
#include <hip/hip_bf16.h>

typedef __attribute__((ext_vector_type(8))) short bf16x8;
typedef __attribute__((ext_vector_type(4))) float f32x4;

// ---------------- workspace layout (bytes) ----------------
// 0        : meta    i32[4]  (0: S counter, 3: loss done-counter)
// 64K      : idx_sel i32[8192]
// 96K      : labels_sel i32[8192]
// 160K     : row_loss f32[8192]
// 256K     : fsel    bf16[8192*1024]   (16 MB)
// 256K+16M : sim     f32[Spad*Spad]

#define OFF_META    0
#define OFF_IDXSEL  (64*1024)
#define OFF_LBLSEL  (96*1024)
#define OFF_RLOSS   (160*1024)
#define OFF_FSEL    (256*1024)

__device__ inline unsigned short f2bf(float f){
    union { __hip_bfloat16 h; unsigned short u; } cv;
    cv.h = __float2bfloat16(f);
    return cv.u;
}

// -------- kernel 1: selection + compaction (1 atomic per block, 32 blocks) --------
__global__ __launch_bounds__(256) void select_kernel(
    const float* __restrict__ score, const int* __restrict__ type_idx,
    const void* __restrict__ labels_raw,
    int* __restrict__ idx_sel, int* __restrict__ labels_sel,
    int* meta, int B)
{
    int tid = threadIdx.x, lane = tid & 63, wid = tid >> 6;
    int row = blockIdx.x * 256 + tid;
    __shared__ int s_is64, s_wcnt[4], s_base;

    // int64 vs int32 label detection: int64 labels in [0,128) have all-zero
    // high words; int32 random labels at odd indices ~never all zero.
    if (wid == 0) {
        int hi = ((const int*)labels_raw)[2 * lane + 1];
        unsigned long long nz = __ballot(hi != 0);
        if (lane == 0) s_is64 = (nz == 0ULL) ? 1 : 0;
    }

    int f = 0;
    if (row < B) {
        float s0 = score[3*row], s1 = score[3*row+1], s2 = score[3*row+2];
        int am = 0; float b = s0;
        if (s1 > b) { b = s1; am = 1; }
        if (s2 > b) { am = 2; }
        f = (am == type_idx[0]) ? 1 : 0;
    }
    unsigned long long m = __ballot(f != 0);
    int incl = __popcll(m & ((2ULL << lane) - 1ULL));
    if (lane == 0) s_wcnt[wid] = __popcll(m);
    __syncthreads();
    if (tid == 0)
        s_base = atomicAdd(&meta[0], s_wcnt[0] + s_wcnt[1] + s_wcnt[2] + s_wcnt[3]);
    __syncthreads();
    if (f) {
        int prefix = 0;
        for (int w = 0; w < wid; w++) prefix += s_wcnt[w];
        int pos = s_base + prefix + incl - 1;
        idx_sel[pos] = row;
        labels_sel[pos] = s_is64 ? (int)((const long long*)labels_raw)[row]
                                 : ((const int*)labels_raw)[row];
    }
}

// -------- kernel 2: fused normalize+gather of selected rows only --------
__global__ __launch_bounds__(256) void gather_kernel(
    const float* __restrict__ feats, const int* __restrict__ idx_sel,
    const int* __restrict__ meta, unsigned short* __restrict__ fsel, int D)
{
    int S = meta[0];
    int Spad = (S + 127) & ~127;
    int s = blockIdx.x * 4 + (threadIdx.x >> 6);
    if (s >= Spad) return;
    int lane = threadIdx.x & 63;
    ushort4* dst = (ushort4*)(fsel + (size_t)s * D);

    if (s >= S) {   // zero padding rows
        ushort4 z = {0,0,0,0};
        for (int i = lane; i < (D >> 2); i += 64) dst[i] = z;
        return;
    }

    int r = idx_sel[s];
    const float4* src = (const float4*)(feats + (size_t)r * D);

    if (D == 1024) {
        float4 v[4];
#pragma unroll
        for (int i = 0; i < 4; i++) v[i] = src[lane + i * 64];
        float ssq = 0.f;
#pragma unroll
        for (int i = 0; i < 4; i++)
            ssq += v[i].x*v[i].x + v[i].y*v[i].y + v[i].z*v[i].z + v[i].w*v[i].w;
        for (int o = 32; o; o >>= 1) ssq += __shfl_down(ssq, o);
        ssq = __shfl(ssq, 0);
        float sc = 1.0f / fmaxf(sqrtf(ssq), 1e-12f);
#pragma unroll
        for (int i = 0; i < 4; i++) {
            ushort4 o;
            o.x = f2bf(v[i].x * sc); o.y = f2bf(v[i].y * sc);
            o.z = f2bf(v[i].z * sc); o.w = f2bf(v[i].w * sc);
            dst[lane + i * 64] = o;
        }
    } else {
        int nv = D >> 2;
        float ssq = 0.f;
        for (int i = lane; i < nv; i += 64) {
            float4 v = src[i];
            ssq += v.x*v.x + v.y*v.y + v.z*v.z + v.w*v.w;
        }
        for (int o = 32; o; o >>= 1) ssq += __shfl_down(ssq, o);
        ssq = __shfl(ssq, 0);
        float sc = 1.0f / fmaxf(sqrtf(ssq), 1e-12f);
        for (int i = lane; i < nv; i += 64) {
            float4 v = src[i];
            ushort4 o;
            o.x = f2bf(v.x * sc); o.y = f2bf(v.y * sc);
            o.z = f2bf(v.z * sc); o.w = f2bf(v.w * sc);
            dst[i] = o;
        }
    }
}

// -------- kernel 3: sim = fsel*fsel^T, persistent blocks over triangle --------
// 128x128 tile, 8 waves, BK=64, TRIPLE-buffered LDS (96 KB), counted vmcnt
// with 2-tiles-ahead prefetch. Grid = 256 persistent blocks looping over
// linearized upper-triangle tile indices (O(1) decode + fixup).
// LDS: per buffer, A/B row-major [128 rows][8 slots][16B]; octet o of row r
// at slot o^(r&7) (swizzle applied on global source; linear LDS dest).
__global__ __launch_bounds__(512) void simgemm_kernel(
    const unsigned short* __restrict__ fsel, const int* __restrict__ meta,
    float* __restrict__ sim, int D)
{
    int S = meta[0];
    int Spad = (S + 127) & ~127;
    int T = Spad >> 7;
    int total = T * (T + 1) / 2;

    __shared__ unsigned short smem[49152];   // 3 bufs x (A 16KB + B 16KB) = 96 KB

    int tid = threadIdx.x;
    int lane = tid & 63;
    int wave = tid >> 6;
    int wr = (wave >> 2) * 64;
    int wc = (wave & 3) * 32;
    int laneRow = lane & 15;
    int laneK = lane >> 4;
    int nt = D >> 6;

#define STAGE(buf, k0, bm_, bn_)                                              \
    _Pragma("unroll")                                                         \
    for (int p = 0; p < 2; p++) {                                             \
        int c = tid + p * 512;                                                \
        int r = c >> 3, slot = c & 7;                                         \
        int og = slot ^ (r & 7);                                              \
        int bb = (buf) * 16384;                                               \
        __builtin_amdgcn_global_load_lds(                                     \
            (const __attribute__((address_space(1))) unsigned int*)           \
                (fsel + (size_t)((bm_) + r) * D + (k0) + og * 8),             \
            (__attribute__((address_space(3))) unsigned int*)&smem[bb + c * 8],\
            16, 0, 0);                                                        \
        __builtin_amdgcn_global_load_lds(                                     \
            (const __attribute__((address_space(1))) unsigned int*)           \
                (fsel + (size_t)((bn_) + r) * D + (k0) + og * 8),             \
            (__attribute__((address_space(3))) unsigned int*)                 \
                &smem[bb + 8192 + c * 8],                                     \
            16, 0, 0);                                                        \
    }

    for (int t = blockIdx.x; t < total; t += gridDim.x) {
        // decode t -> (ti, tj), ti <= tj
        float bq = 2.0f * T + 1.0f;
        int ti = (int)((bq - sqrtf(bq * bq - 8.0f * (float)t)) * 0.5f);
        if (ti >= T) ti = T - 1;
        while (ti > 0 && (ti * T - ti * (ti - 1) / 2) > t) ti--;
        while (((ti + 1) * T - (ti + 1) * ti / 2) <= t) ti++;
        int tj = ti + (t - (ti * T - ti * (ti - 1) / 2));
        int bm = ti << 7, bn = tj << 7;

        f32x4 acc[4][2];
#pragma unroll
        for (int m = 0; m < 4; m++)
#pragma unroll
            for (int n = 0; n < 2; n++)
                acc[m][n] = (f32x4){0.f, 0.f, 0.f, 0.f};

        STAGE(0, 0, bm, bn)
        if (nt > 1) STAGE(1, 64, bm, bn)

        for (int k = 0; k < nt; k++) {
            if (k + 2 < nt) STAGE((k + 2) % 3, (k + 2) << 6, bm, bn)
            int rem = nt - 1 - k;
            if (rem >= 2)      asm volatile("s_waitcnt vmcnt(8)" ::: "memory");
            else if (rem == 1) asm volatile("s_waitcnt vmcnt(4)" ::: "memory");
            else               asm volatile("s_waitcnt vmcnt(0)" ::: "memory");
            __builtin_amdgcn_s_barrier();
            __builtin_amdgcn_sched_barrier(0);

            int bb = (k % 3) * 16384;
            bf16x8 af[2][4], bfr[2][2];
#pragma unroll
            for (int s2 = 0; s2 < 2; s2++) {
                int o = s2 * 4 + laneK;
#pragma unroll
                for (int m = 0; m < 4; m++) {
                    int row = wr + m * 16 + laneRow;
                    af[s2][m] = *(const bf16x8*)&smem[bb + (row * 8 + (o ^ (row & 7))) * 8];
                }
#pragma unroll
                for (int n = 0; n < 2; n++) {
                    int row = wc + n * 16 + laneRow;
                    bfr[s2][n] = *(const bf16x8*)&smem[bb + 8192 + (row * 8 + (o ^ (row & 7))) * 8];
                }
            }
#pragma unroll
            for (int s2 = 0; s2 < 2; s2++)
#pragma unroll
                for (int m = 0; m < 4; m++)
#pragma unroll
                    for (int n = 0; n < 2; n++)
                        acc[m][n] = __builtin_amdgcn_mfma_f32_16x16x32_bf16(
                            af[s2][m], bfr[s2][n], acc[m][n], 0, 0, 0);

            __builtin_amdgcn_sched_barrier(0);
            __builtin_amdgcn_s_barrier();   // safe to overwrite this buf next
        }

        // C/D layout: col = lane&15, row = (lane>>4)*4 + q
#pragma unroll
        for (int m = 0; m < 4; m++) {
            int row0 = bm + wr + m * 16 + (lane >> 4) * 4;
#pragma unroll
            for (int n = 0; n < 2; n++) {
                int col = bn + wc + n * 16 + laneRow;
#pragma unroll
                for (int q = 0; q < 4; q++)
                    sim[(size_t)(row0 + q) * Spad + col] = acc[m][n][q];
                if (bm != bn) {   // mirror into lower triangle
                    *(f32x4*)&sim[(size_t)col * Spad + row0] = acc[m][n];
                }
            }
        }
    }
#undef STAGE
}

// -------- kernel 4: wave-per-row loss + last-block final reduction --------
__global__ __launch_bounds__(256) void loss_kernel(
    const float* __restrict__ sim, const int* __restrict__ labels_sel,
    int* __restrict__ meta, float* __restrict__ row_loss,
    float* out, float invB)
{
    int S = meta[0];
    int Spad = (S + 127) & ~127;
    int tid = threadIdx.x;
    __shared__ unsigned char slbl[8192];
    __shared__ float sm[4];
    __shared__ int isLast;

    bool blockActive = ((int)blockIdx.x * 4 < S);
    if (blockActive) {
        for (int j = tid; j < Spad; j += 256)
            slbl[j] = (j < S) ? (unsigned char)labels_sel[j] : 0xFF;
        __syncthreads();

        int lane = tid & 63;
        int s = blockIdx.x * 4 + (tid >> 6);
        if (s < S) {
            const float4* rowv = (const float4*)(sim + (size_t)s * Spad);
            const unsigned* lblv = (const unsigned*)slbl;
            const float ONE_ME = 1.0f - 1e-5f;
            int lbl = slbl[s];
            int nv = Spad >> 2;
            float rl = 0.f;

            if (nv <= 704) {   // register-cached: 11 float4 = one sim read
                float4 rv[11];
                unsigned lw[11];
#pragma unroll
                for (int i = 0; i < 11; i++) {
                    int j4 = lane + i * 64;
                    if (j4 < nv) { rv[i] = rowv[j4]; lw[i] = lblv[j4]; }
                    else         { rv[i] = (float4){0,0,0,0}; lw[i] = 0xFFFFFFFFu; }
                }
                int cnt = 0;
                float minp = INFINITY, maxn = -INFINITY;
#pragma unroll
                for (int i = 0; i < 11; i++) {
                    int j0 = (lane + i * 64) << 2;
#pragma unroll
                    for (int e = 0; e < 4; e++) {
                        float sv = (&rv[i].x)[e];
                        if (j0 + e == s) sv = 1.0f;
                        int lb = (lw[i] >> (8 * e)) & 0xFF;
                        if (lb == lbl) {
                            cnt++;
                            if (sv < ONE_ME) minp = fminf(minp, sv);
                        } else if (lb != 0xFF) {
                            maxn = fmaxf(maxn, sv);
                        }
                    }
                }
                for (int o = 32; o; o >>= 1) {
                    cnt += __shfl_down(cnt, o);
                    minp = fminf(minp, __shfl_down(minp, o));
                    maxn = fmaxf(maxn, __shfl_down(maxn, o));
                }
                cnt  = __shfl(cnt, 0);
                minp = __shfl(minp, 0);
                maxn = __shfl(maxn, 0);

                if (cnt > 1 && minp < 3e38f && maxn > -3e38f) {
                    float psum = 0.f, nsum = 0.f;
#pragma unroll
                    for (int i = 0; i < 11; i++) {
                        int j0 = (lane + i * 64) << 2;
#pragma unroll
                        for (int e = 0; e < 4; e++) {
                            float sv = (&rv[i].x)[e];
                            if (j0 + e == s) sv = 1.0f;
                            int lb = (lw[i] >> (8 * e)) & 0xFF;
                            if (lb == lbl) {
                                if (sv < ONE_ME && sv - 0.1f < maxn)
                                    psum += __expf(-2.0f * (sv - 0.5f));
                            } else if (lb != 0xFF) {
                                if (sv + 0.1f > minp)
                                    nsum += __expf(40.0f * (sv - 0.5f));
                            }
                        }
                    }
                    for (int o = 32; o; o >>= 1) {
                        psum += __shfl_down(psum, o);
                        nsum += __shfl_down(nsum, o);
                    }
                    if (psum > 0.f && nsum > 0.f)
                        rl = log1pf(psum) * 0.5f + log1pf(nsum) * 0.025f;
                }
            } else {   // streaming fallback for large S
                int cnt = 0;
                float minp = INFINITY, maxn = -INFINITY;
                for (int j4 = lane; j4 < nv; j4 += 64) {
                    float4 v = rowv[j4];
                    unsigned w = lblv[j4];
#pragma unroll
                    for (int e = 0; e < 4; e++) {
                        int j = (j4 << 2) + e;
                        float sv = (&v.x)[e];
                        if (j == s) sv = 1.0f;
                        int lb = (w >> (8 * e)) & 0xFF;
                        if (lb == lbl) {
                            cnt++;
                            if (sv < ONE_ME) minp = fminf(minp, sv);
                        } else if (lb != 0xFF) {
                            maxn = fmaxf(maxn, sv);
                        }
                    }
                }
                for (int o = 32; o; o >>= 1) {
                    cnt += __shfl_down(cnt, o);
                    minp = fminf(minp, __shfl_down(minp, o));
                    maxn = fmaxf(maxn, __shfl_down(maxn, o));
                }
                cnt  = __shfl(cnt, 0);
                minp = __shfl(minp, 0);
                maxn = __shfl(maxn, 0);

                if (cnt > 1 && minp < 3e38f && maxn > -3e38f) {
                    float psum = 0.f, nsum = 0.f;
                    for (int j4 = lane; j4 < nv; j4 += 64) {
                        float4 v = rowv[j4];
                        unsigned w = lblv[j4];
#pragma unroll
                        for (int e = 0; e < 4; e++) {
                            int j = (j4 << 2) + e;
                            float sv = (&v.x)[e];
                            if (j == s) sv = 1.0f;
                            int lb = (w >> (8 * e)) & 0xFF;
                            if (lb == lbl) {
                                if (sv < ONE_ME && sv - 0.1f < maxn)
                                    psum += __expf(-2.0f * (sv - 0.5f));
                            } else if (lb != 0xFF) {
                                if (sv + 0.1f > minp)
                                    nsum += __expf(40.0f * (sv - 0.5f));
                            }
                        }
                    }
                    for (int o = 32; o; o >>= 1) {
                        psum += __shfl_down(psum, o);
                        nsum += __shfl_down(nsum, o);
                    }
                    if (psum > 0.f && nsum > 0.f)
                        rl = log1pf(psum) * 0.5f + log1pf(nsum) * 0.025f;
                }
            }
            if (lane == 0) row_loss[s] = rl;
        }
    }

    // last-block final reduction (every block participates in the count)
    if (tid == 0) {
        __threadfence();
        int done = atomicAdd(&meta[3], 1);
        isLast = (done == (int)gridDim.x - 1) ? 1 : 0;
    }
    __syncthreads();
    if (isLast) {
        float sum = 0.f;
        for (int j = tid; j < S; j += 256) sum += row_loss[j];
        for (int o = 32; o; o >>= 1) sum += __shfl_down(sum, o);
        if ((tid & 63) == 0) sm[tid >> 6] = sum;
        __syncthreads();
        if (tid == 0) out[0] = (sm[0] + sm[1] + sm[2] + sm[3]) * invB;
    }
}

extern "C" void kernel_launch(void* const* d_in, const int* in_sizes, int n_in,
                              void* d_out, int out_size, void* d_ws, size_t ws_size,
                              hipStream_t stream)
{
    const float* feats    = (const float*)d_in[0];
    const void*  labels   = d_in[1];
    const float* score    = (const float*)d_in[2];
    const int*   type_idx = (const int*)d_in[3];

    int B = in_sizes[1];           // 8192
    int D = in_sizes[0] / B;       // 1024

    char* ws = (char*)d_ws;
    int*   meta       = (int*)  (ws + OFF_META);
    int*   idx_sel    = (int*)  (ws + OFF_IDXSEL);
    int*   labels_sel = (int*)  (ws + OFF_LBLSEL);
    float* row_loss   = (float*)(ws + OFF_RLOSS);
    unsigned short* fsel = (unsigned short*)(ws + OFF_FSEL);
    float* sim        = (float*)(ws + OFF_FSEL + (size_t)B * D * 2);
    float* out        = (float*)d_out;

    (void)hipMemsetAsync(meta, 0, 16, stream);

    select_kernel<<<(B + 255) / 256, 256, 0, stream>>>(score, type_idx, labels,
                                                       idx_sel, labels_sel, meta, B);
    gather_kernel<<<B / 4, 256, 0, stream>>>(feats, idx_sel, meta, fsel, D);
    simgemm_kernel<<<256, 512, 0, stream>>>(fsel, meta, sim, D);
    loss_kernel<<<B / 4, 256, 0, stream>>>(sim, labels_sel, meta, row_loss,
                                           out, 1.0f / (float)B);
}

// Round 12
// 117.823 us; speedup vs baseline: 1.2490x; 1.2490x over previous
//
#include <hip/hip_runtime.h>
#include <hip/hip_bf16.h>

typedef __attribute__((ext_vector_type(8))) short bf16x8;
typedef __attribute__((ext_vector_type(4))) float f32x4;

// ---------------- workspace layout (bytes) ----------------
// 0        : meta    i32[4]  (0: S counter)
// 64K      : idx_sel i32[8192]
// 96K      : labels_sel i32[8192]
// 128K     : labels_byte u8[8192] (pad = 0xFF)
// 160K     : row_loss f32[8192]
// 256K     : fsel    bf16[8192*1024]   (16 MB)
// 256K+16M : sim     f32[Spad*Spad]

#define OFF_META    0
#define OFF_IDXSEL  (64*1024)
#define OFF_LBLSEL  (96*1024)
#define OFF_LBLBYTE (128*1024)
#define OFF_RLOSS   (160*1024)
#define OFF_FSEL    (256*1024)

__device__ inline unsigned short f2bf(float f){
    union { __hip_bfloat16 h; unsigned short u; } cv;
    cv.h = __float2bfloat16(f);
    return cv.u;
}

// -------- kernel 1: selection + compaction (1 atomic per block, 32 blocks) --------
__global__ __launch_bounds__(256) void select_kernel(
    const float* __restrict__ score, const int* __restrict__ type_idx,
    const void* __restrict__ labels_raw,
    int* __restrict__ idx_sel, int* __restrict__ labels_sel,
    unsigned char* __restrict__ labels_byte,
    int* meta, int B)
{
    int tid = threadIdx.x, lane = tid & 63, wid = tid >> 6;
    int row = blockIdx.x * 256 + tid;
    __shared__ int s_is64, s_wcnt[4], s_base;

    // int64 vs int32 label detection: int64 labels in [0,128) have all-zero
    // high words; int32 random labels at odd indices ~never all zero.
    if (wid == 0) {
        int hi = ((const int*)labels_raw)[2 * lane + 1];
        unsigned long long nz = __ballot(hi != 0);
        if (lane == 0) s_is64 = (nz == 0ULL) ? 1 : 0;
    }

    int f = 0;
    if (row < B) {
        float s0 = score[3*row], s1 = score[3*row+1], s2 = score[3*row+2];
        int am = 0; float b = s0;
        if (s1 > b) { b = s1; am = 1; }
        if (s2 > b) { am = 2; }
        f = (am == type_idx[0]) ? 1 : 0;
    }
    unsigned long long m = __ballot(f != 0);
    int incl = __popcll(m & ((2ULL << lane) - 1ULL));
    if (lane == 0) s_wcnt[wid] = __popcll(m);
    __syncthreads();
    if (tid == 0)
        s_base = atomicAdd(&meta[0], s_wcnt[0] + s_wcnt[1] + s_wcnt[2] + s_wcnt[3]);
    __syncthreads();
    if (f) {
        int prefix = 0;
        for (int w = 0; w < wid; w++) prefix += s_wcnt[w];
        int pos = s_base + prefix + incl - 1;
        int lv = s_is64 ? (int)((const long long*)labels_raw)[row]
                        : ((const int*)labels_raw)[row];
        idx_sel[pos] = row;
        labels_sel[pos] = lv;
        labels_byte[pos] = (unsigned char)lv;   // labels in [0,128) fit a byte
    }
}

// -------- kernel 2: fused normalize+gather of selected rows only --------
__global__ __launch_bounds__(256) void gather_kernel(
    const float* __restrict__ feats, const int* __restrict__ idx_sel,
    const int* __restrict__ meta, unsigned short* __restrict__ fsel, int D)
{
    int S = meta[0];
    int Spad = (S + 127) & ~127;
    int s = blockIdx.x * 4 + (threadIdx.x >> 6);
    if (s >= Spad) return;
    int lane = threadIdx.x & 63;
    ushort4* dst = (ushort4*)(fsel + (size_t)s * D);

    if (s >= S) {   // zero padding rows
        ushort4 z = {0,0,0,0};
        for (int i = lane; i < (D >> 2); i += 64) dst[i] = z;
        return;
    }

    int r = idx_sel[s];
    const float4* src = (const float4*)(feats + (size_t)r * D);

    if (D == 1024) {
        float4 v[4];
#pragma unroll
        for (int i = 0; i < 4; i++) v[i] = src[lane + i * 64];
        float ssq = 0.f;
#pragma unroll
        for (int i = 0; i < 4; i++)
            ssq += v[i].x*v[i].x + v[i].y*v[i].y + v[i].z*v[i].z + v[i].w*v[i].w;
        for (int o = 32; o; o >>= 1) ssq += __shfl_down(ssq, o);
        ssq = __shfl(ssq, 0);
        float sc = 1.0f / fmaxf(sqrtf(ssq), 1e-12f);
#pragma unroll
        for (int i = 0; i < 4; i++) {
            ushort4 o;
            o.x = f2bf(v[i].x * sc); o.y = f2bf(v[i].y * sc);
            o.z = f2bf(v[i].z * sc); o.w = f2bf(v[i].w * sc);
            dst[lane + i * 64] = o;
        }
    } else {
        int nv = D >> 2;
        float ssq = 0.f;
        for (int i = lane; i < nv; i += 64) {
            float4 v = src[i];
            ssq += v.x*v.x + v.y*v.y + v.z*v.z + v.w*v.w;
        }
        for (int o = 32; o; o >>= 1) ssq += __shfl_down(ssq, o);
        ssq = __shfl(ssq, 0);
        float sc = 1.0f / fmaxf(sqrtf(ssq), 1e-12f);
        for (int i = lane; i < nv; i += 64) {
            float4 v = src[i];
            ushort4 o;
            o.x = f2bf(v.x * sc); o.y = f2bf(v.y * sc);
            o.z = f2bf(v.z * sc); o.w = f2bf(v.w * sc);
            dst[i] = o;
        }
    }
}

// -------- kernel 3: sim = fsel*fsel^T, persistent blocks over triangle --------
// 128x128 tile, 8 waves, BK=64, TRIPLE-buffered LDS (96 KB), counted vmcnt
// with 2-tiles-ahead prefetch. Grid = 256 persistent blocks looping over
// linearized upper-triangle tile indices.
__global__ __launch_bounds__(512) void simgemm_kernel(
    const unsigned short* __restrict__ fsel, const int* __restrict__ meta,
    float* __restrict__ sim, int D)
{
    int S = meta[0];
    int Spad = (S + 127) & ~127;
    int T = Spad >> 7;
    int total = T * (T + 1) / 2;

    __shared__ unsigned short smem[49152];   // 3 bufs x (A 16KB + B 16KB) = 96 KB

    int tid = threadIdx.x;
    int lane = tid & 63;
    int wave = tid >> 6;
    int wr = (wave >> 2) * 64;
    int wc = (wave & 3) * 32;
    int laneRow = lane & 15;
    int laneK = lane >> 4;
    int nt = D >> 6;

#define STAGE(buf, k0, bm_, bn_)                                              \
    _Pragma("unroll")                                                         \
    for (int p = 0; p < 2; p++) {                                             \
        int c = tid + p * 512;                                                \
        int r = c >> 3, slot = c & 7;                                         \
        int og = slot ^ (r & 7);                                              \
        int bb = (buf) * 16384;                                               \
        __builtin_amdgcn_global_load_lds(                                     \
            (const __attribute__((address_space(1))) unsigned int*)           \
                (fsel + (size_t)((bm_) + r) * D + (k0) + og * 8),             \
            (__attribute__((address_space(3))) unsigned int*)&smem[bb + c * 8],\
            16, 0, 0);                                                        \
        __builtin_amdgcn_global_load_lds(                                     \
            (const __attribute__((address_space(1))) unsigned int*)           \
                (fsel + (size_t)((bn_) + r) * D + (k0) + og * 8),             \
            (__attribute__((address_space(3))) unsigned int*)                 \
                &smem[bb + 8192 + c * 8],                                     \
            16, 0, 0);                                                        \
    }

    for (int t = blockIdx.x; t < total; t += gridDim.x) {
        // decode t -> (ti, tj), ti <= tj
        float bq = 2.0f * T + 1.0f;
        int ti = (int)((bq - sqrtf(bq * bq - 8.0f * (float)t)) * 0.5f);
        if (ti >= T) ti = T - 1;
        while (ti > 0 && (ti * T - ti * (ti - 1) / 2) > t) ti--;
        while (((ti + 1) * T - (ti + 1) * ti / 2) <= t) ti++;
        int tj = ti + (t - (ti * T - ti * (ti - 1) / 2));
        int bm = ti << 7, bn = tj << 7;

        f32x4 acc[4][2];
#pragma unroll
        for (int m = 0; m < 4; m++)
#pragma unroll
            for (int n = 0; n < 2; n++)
                acc[m][n] = (f32x4){0.f, 0.f, 0.f, 0.f};

        STAGE(0, 0, bm, bn)
        if (nt > 1) STAGE(1, 64, bm, bn)

        for (int k = 0; k < nt; k++) {
            if (k + 2 < nt) STAGE((k + 2) % 3, (k + 2) << 6, bm, bn)
            int rem = nt - 1 - k;
            if (rem >= 2)      asm volatile("s_waitcnt vmcnt(8)" ::: "memory");
            else if (rem == 1) asm volatile("s_waitcnt vmcnt(4)" ::: "memory");
            else               asm volatile("s_waitcnt vmcnt(0)" ::: "memory");
            __builtin_amdgcn_s_barrier();
            __builtin_amdgcn_sched_barrier(0);

            int bb = (k % 3) * 16384;
            bf16x8 af[2][4], bfr[2][2];
#pragma unroll
            for (int s2 = 0; s2 < 2; s2++) {
                int o = s2 * 4 + laneK;
#pragma unroll
                for (int m = 0; m < 4; m++) {
                    int row = wr + m * 16 + laneRow;
                    af[s2][m] = *(const bf16x8*)&smem[bb + (row * 8 + (o ^ (row & 7))) * 8];
                }
#pragma unroll
                for (int n = 0; n < 2; n++) {
                    int row = wc + n * 16 + laneRow;
                    bfr[s2][n] = *(const bf16x8*)&smem[bb + 8192 + (row * 8 + (o ^ (row & 7))) * 8];
                }
            }
#pragma unroll
            for (int s2 = 0; s2 < 2; s2++)
#pragma unroll
                for (int m = 0; m < 4; m++)
#pragma unroll
                    for (int n = 0; n < 2; n++)
                        acc[m][n] = __builtin_amdgcn_mfma_f32_16x16x32_bf16(
                            af[s2][m], bfr[s2][n], acc[m][n], 0, 0, 0);

            __builtin_amdgcn_sched_barrier(0);
            __builtin_amdgcn_s_barrier();   // safe to overwrite this buf next
        }

        // C/D layout: col = lane&15, row = (lane>>4)*4 + q
#pragma unroll
        for (int m = 0; m < 4; m++) {
            int row0 = bm + wr + m * 16 + (lane >> 4) * 4;
#pragma unroll
            for (int n = 0; n < 2; n++) {
                int col = bn + wc + n * 16 + laneRow;
#pragma unroll
                for (int q = 0; q < 4; q++)
                    sim[(size_t)(row0 + q) * Spad + col] = acc[m][n][q];
                if (bm != bn) {   // mirror into lower triangle
                    *(f32x4*)&sim[(size_t)col * Spad + row0] = acc[m][n];
                }
            }
        }
    }
#undef STAGE
}

// -------- kernel 4: wave-per-row loss -> row_loss[s] --------
// No LDS, no syncthreads, no atomics. Labels read byte-packed from global
// (2.8 KB, L1-resident). Row cached in 11 float4 regs (Spad<=2816),
// streaming fallback otherwise.
__global__ __launch_bounds__(256) void loss_kernel(
    const float* __restrict__ sim, const unsigned char* __restrict__ labels_byte,
    const int* __restrict__ meta, float* __restrict__ row_loss)
{
    int S = meta[0];
    if ((int)blockIdx.x * 4 >= S) return;
    int Spad = (S + 127) & ~127;
    int tid = threadIdx.x;
    int lane = tid & 63;
    int s = blockIdx.x * 4 + (tid >> 6);
    if (s >= S) return;

    const float4* rowv = (const float4*)(sim + (size_t)s * Spad);
    const unsigned* lblv = (const unsigned*)labels_byte;
    const float ONE_ME = 1.0f - 1e-5f;
    int lbl = labels_byte[s];
    int nv = Spad >> 2;
    float rl = 0.f;

    if (nv <= 704) {   // register-cached: 11 float4 = one sim read
        float4 rv[11];
        unsigned lw[11];
#pragma unroll
        for (int i = 0; i < 11; i++) {
            int j4 = lane + i * 64;
            if (j4 < nv) { rv[i] = rowv[j4]; lw[i] = lblv[j4]; }
            else         { rv[i] = (float4){0,0,0,0}; lw[i] = 0xFFFFFFFFu; }
        }
        int cnt = 0;
        float minp = INFINITY, maxn = -INFINITY;
#pragma unroll
        for (int i = 0; i < 11; i++) {
            int j0 = (lane + i * 64) << 2;
#pragma unroll
            for (int e = 0; e < 4; e++) {
                float sv = (&rv[i].x)[e];
                if (j0 + e == s) sv = 1.0f;
                int lb = (lw[i] >> (8 * e)) & 0xFF;
                if (lb == lbl) {
                    cnt++;
                    if (sv < ONE_ME) minp = fminf(minp, sv);
                } else if (lb != 0xFF) {
                    maxn = fmaxf(maxn, sv);
                }
            }
        }
        for (int o = 32; o; o >>= 1) {
            cnt += __shfl_down(cnt, o);
            minp = fminf(minp, __shfl_down(minp, o));
            maxn = fmaxf(maxn, __shfl_down(maxn, o));
        }
        cnt  = __shfl(cnt, 0);
        minp = __shfl(minp, 0);
        maxn = __shfl(maxn, 0);

        if (cnt > 1 && minp < 3e38f && maxn > -3e38f) {
            float psum = 0.f, nsum = 0.f;
#pragma unroll
            for (int i = 0; i < 11; i++) {
                int j0 = (lane + i * 64) << 2;
#pragma unroll
                for (int e = 0; e < 4; e++) {
                    float sv = (&rv[i].x)[e];
                    if (j0 + e == s) sv = 1.0f;
                    int lb = (lw[i] >> (8 * e)) & 0xFF;
                    if (lb == lbl) {
                        if (sv < ONE_ME && sv - 0.1f < maxn)
                            psum += __expf(-2.0f * (sv - 0.5f));
                    } else if (lb != 0xFF) {
                        if (sv + 0.1f > minp)
                            nsum += __expf(40.0f * (sv - 0.5f));
                    }
                }
            }
            for (int o = 32; o; o >>= 1) {
                psum += __shfl_down(psum, o);
                nsum += __shfl_down(nsum, o);
            }
            if (psum > 0.f && nsum > 0.f)
                rl = log1pf(psum) * 0.5f + log1pf(nsum) * 0.025f;
        }
    } else {   // streaming fallback for large S
        int cnt = 0;
        float minp = INFINITY, maxn = -INFINITY;
        for (int j4 = lane; j4 < nv; j4 += 64) {
            float4 v = rowv[j4];
            unsigned w = lblv[j4];
#pragma unroll
            for (int e = 0; e < 4; e++) {
                int j = (j4 << 2) + e;
                float sv = (&v.x)[e];
                if (j == s) sv = 1.0f;
                int lb = (w >> (8 * e)) & 0xFF;
                if (lb == lbl) {
                    cnt++;
                    if (sv < ONE_ME) minp = fminf(minp, sv);
                } else if (lb != 0xFF) {
                    maxn = fmaxf(maxn, sv);
                }
            }
        }
        for (int o = 32; o; o >>= 1) {
            cnt += __shfl_down(cnt, o);
            minp = fminf(minp, __shfl_down(minp, o));
            maxn = fmaxf(maxn, __shfl_down(maxn, o));
        }
        cnt  = __shfl(cnt, 0);
        minp = __shfl(minp, 0);
        maxn = __shfl(maxn, 0);

        if (cnt > 1 && minp < 3e38f && maxn > -3e38f) {
            float psum = 0.f, nsum = 0.f;
            for (int j4 = lane; j4 < nv; j4 += 64) {
                float4 v = rowv[j4];
                unsigned w = lblv[j4];
#pragma unroll
                for (int e = 0; e < 4; e++) {
                    int j = (j4 << 2) + e;
                    float sv = (&v.x)[e];
                    if (j == s) sv = 1.0f;
                    int lb = (w >> (8 * e)) & 0xFF;
                    if (lb == lbl) {
                        if (sv < ONE_ME && sv - 0.1f < maxn)
                            psum += __expf(-2.0f * (sv - 0.5f));
                    } else if (lb != 0xFF) {
                        if (sv + 0.1f > minp)
                            nsum += __expf(40.0f * (sv - 0.5f));
                    }
                }
            }
            for (int o = 32; o; o >>= 1) {
                psum += __shfl_down(psum, o);
                nsum += __shfl_down(nsum, o);
            }
            if (psum > 0.f && nsum > 0.f)
                rl = log1pf(psum) * 0.5f + log1pf(nsum) * 0.025f;
        }
    }
    if (lane == 0) row_loss[s] = rl;
}

// -------- kernel 5: final reduction of row_loss (1 block) --------
__global__ __launch_bounds__(256) void reduce_kernel(
    const float* __restrict__ row_loss, const int* __restrict__ meta,
    float* out, float invB)
{
    int S = meta[0];
    float sum = 0.f;
    for (int j = threadIdx.x; j < S; j += 256) sum += row_loss[j];
    for (int o = 32; o; o >>= 1) sum += __shfl_down(sum, o);
    __shared__ float sm[4];
    if ((threadIdx.x & 63) == 0) sm[threadIdx.x >> 6] = sum;
    __syncthreads();
    if (threadIdx.x == 0) out[0] = (sm[0] + sm[1] + sm[2] + sm[3]) * invB;
}

extern "C" void kernel_launch(void* const* d_in, const int* in_sizes, int n_in,
                              void* d_out, int out_size, void* d_ws, size_t ws_size,
                              hipStream_t stream)
{
    const float* feats    = (const float*)d_in[0];
    const void*  labels   = d_in[1];
    const float* score    = (const float*)d_in[2];
    const int*   type_idx = (const int*)d_in[3];

    int B = in_sizes[1];           // 8192
    int D = in_sizes[0] / B;       // 1024

    char* ws = (char*)d_ws;
    int*   meta       = (int*)  (ws + OFF_META);
    int*   idx_sel    = (int*)  (ws + OFF_IDXSEL);
    int*   labels_sel = (int*)  (ws + OFF_LBLSEL);
    unsigned char* labels_byte = (unsigned char*)(ws + OFF_LBLBYTE);
    float* row_loss   = (float*)(ws + OFF_RLOSS);
    unsigned short* fsel = (unsigned short*)(ws + OFF_FSEL);
    float* sim        = (float*)(ws + OFF_FSEL + (size_t)B * D * 2);
    float* out        = (float*)d_out;

    (void)hipMemsetAsync(meta, 0, 16, stream);
    (void)hipMemsetAsync(labels_byte, 0xFF, 8192, stream);   // pad sentinel

    select_kernel<<<(B + 255) / 256, 256, 0, stream>>>(score, type_idx, labels,
                                                       idx_sel, labels_sel,
                                                       labels_byte, meta, B);
    gather_kernel<<<B / 4, 256, 0, stream>>>(feats, idx_sel, meta, fsel, D);
    simgemm_kernel<<<256, 512, 0, stream>>>(fsel, meta, sim, D);
    loss_kernel<<<B / 4, 256, 0, stream>>>(sim, labels_byte, meta, row_loss);
    reduce_kernel<<<1, 256, 0, stream>>>(row_loss, meta, out, 1.0f / (float)B);
}